// Round 7
// baseline (397.096 us; speedup 1.0000x reference)
//
#include <hip/hip_runtime.h>

// CascadedAttentionCell: B=64, T=512, D=1024, OUT=1024 (all fp32 in/out)
// R7: gemm reverted to R4 (barrier-free fragment GEMM, depth-1 ping-pong --
// best measured 98us; R5 depth-4 and R6 LDS-staging both disproved as wins).
// This round attacks the 265us of non-gemm: pack_a rewritten as LDS-transpose
// with coalesced reads AND writes (~192MB pure BW); was_part+was_reduce fused
// into one LDS-resident kernel (no global RMW sweeps).

typedef _Float16 h8 __attribute__((ext_vector_type(8)));
typedef float f16v __attribute__((ext_vector_type(16)));

__device__ __forceinline__ float tanh_fast(float x) {
    float e = __expf(2.0f * x);
    return 1.0f - 2.0f * __builtin_amdgcn_rcpf(e + 1.0f);
}

// ---- pack Ua (fp32 [K=1024][N=1024]) into fp16 B-fragment order ----
__global__ __launch_bounds__(256) void k_pack_ua(const float* __restrict__ Ua,
                                                 _Float16* __restrict__ B16) {
    int t = blockIdx.x * 256 + threadIdx.x;   // 0..131071
    int nn = t & 31, kg = (t >> 5) & 1, ks = (t >> 6) & 63, nt = t >> 12;
    int n = (nt << 5) + nn;
    int kbase = (ks << 4) + (kg << 3);
    h8 v;
#pragma unroll
    for (int j = 0; j < 8; ++j) v[j] = (_Float16)Ua[(size_t)(kbase + j) * 1024 + n];
    *(h8*)(B16 + ((size_t)t << 3)) = v;
}

// ---- pack inputs -> fp16 A-fragment order via LDS transpose ----
// Block bx: rows [bx*32,+32), 4 chunks of 256 k. Stage: coalesced float4 reads
// (64 consecutive float4 per row). Emit: fragment-order h8, consecutive lanes
// -> consecutive 16B global writes. LDS row stride 65 float4 (pad).
#define PA_STR 65
__global__ __launch_bounds__(256) void k_pack_a(const float* __restrict__ inputs,
                                                _Float16* __restrict__ A16) {
    __shared__ float4 T[32 * PA_STR];
    const int bx = blockIdx.x, t = threadIdx.x;
    const size_t r0 = (size_t)bx * 32;
    h8* outBase = (h8*)A16 + ((size_t)bx << 12);
#pragma unroll 1
    for (int kc = 0; kc < 4; ++kc) {
        if (kc) __syncthreads();
#pragma unroll
        for (int i = 0; i < 8; ++i) {
            int p = (i << 8) + t;               // 0..2047
            int row = p >> 6, c4 = p & 63;
            T[row * PA_STR + c4] =
                ((const float4*)(inputs + (r0 + row) * 1024 + (kc << 8)))[c4];
        }
        __syncthreads();
#pragma unroll
        for (int i = 0; i < 4; ++i) {
            int p = (i << 8) + t;               // 0..1023
            int ks8 = p >> 6, l = p & 63;
            int row = l & 31, k8 = l >> 5;
            float4 v0 = T[row * PA_STR + (ks8 << 2) + (k8 << 1)];
            float4 v1 = T[row * PA_STR + (ks8 << 2) + (k8 << 1) + 1];
            outBase[(((kc << 4) + ks8) << 6) + l] =
                (h8){ (_Float16)v0.x, (_Float16)v0.y, (_Float16)v0.z, (_Float16)v0.w,
                      (_Float16)v1.x, (_Float16)v1.y, (_Float16)v1.z, (_Float16)v1.w };
        }
    }
}

// ---- wsWaS[b][p] = Ba[p] + sum_o ps[b][o]*Wa[o][p], fused one-pass ----
// grid 64 = (bg<<3)|cg : batches [bg*8,+8), float4-cols [cg*32,+32).
// ps slab (8x1024) in LDS; Wa streamed coalesced; acc in registers.
__global__ __launch_bounds__(256) void k_was(const float* __restrict__ ps,
                                             const float* __restrict__ Wa,
                                             const float* __restrict__ Ba,
                                             float* __restrict__ wsWaS) {
    __shared__ float psL[8][1024];
    const int bg = blockIdx.x >> 3, cg = blockIdx.x & 7;
    const int t = threadIdx.x;
#pragma unroll
    for (int i = 0; i < 8; ++i)
        ((float4*)psL[i])[t] = ((const float4*)(ps + (size_t)(bg * 8 + i) * 1024))[t];
    __syncthreads();
    const int c4 = (cg << 5) + (t & 31);
    const int br = t >> 5;
    const float4* WaC = (const float4*)Wa + c4;
    const float* prow = psL[br];
    float4 acc = ((const float4*)Ba)[c4];
#pragma unroll 8
    for (int o = 0; o < 1024; ++o) {
        float s = prow[o];
        float4 w = WaC[(size_t)o * 256];
        acc.x += s * w.x; acc.y += s * w.y; acc.z += s * w.z; acc.w += s * w.w;
    }
    ((float4*)wsWaS)[(size_t)(bg * 8 + br) * 256 + c4] = acc;
}

// ---- fused GEMM (R4 verbatim): barrier-free, depth-1 ping-pong ----
__global__ __launch_bounds__(256, 2) void k_fused_gemm(
    const _Float16* __restrict__ A16, const _Float16* __restrict__ B16,
    const float* __restrict__ wsWaS, const float* __restrict__ Va,
    float* __restrict__ scores)
{
    __shared__ float scoreSh[64];
    const int tid = threadIdx.x;
    const int lane = tid & 63, wv = tid >> 6;
    const int l31 = lane & 31, lhi = lane >> 5;
    const int r0 = blockIdx.x * 64;
    const int rb0 = blockIdx.x * 2;
    const int b = r0 >> 9;

    if (tid < 64) scoreSh[tid] = 0.0f;
    __syncthreads();

    const h8* A8 = (const h8*)A16;
    const h8* B8 = (const h8*)B16;
    const h8* aBase = A8 + ((size_t)rb0 << 12) + lane;

    for (int pass = 0; pass < 2; ++pass) {
        const int ntb = (pass << 4) + (wv << 2);
        const h8* bBase = B8 + ((size_t)ntb << 12) + lane;

        f16v acc[2][4];
#pragma unroll
        for (int rt = 0; rt < 2; ++rt)
#pragma unroll
            for (int ct = 0; ct < 4; ++ct)
#pragma unroll
                for (int e = 0; e < 16; ++e) acc[rt][ct][e] = 0.0f;

        h8 af[2][2], bf[2][4];
#pragma unroll
        for (int rt = 0; rt < 2; ++rt) af[0][rt] = aBase[rt * 4096];
#pragma unroll
        for (int ct = 0; ct < 4; ++ct) bf[0][ct] = bBase[ct * 4096];

#pragma unroll 4
        for (int ks = 0; ks < 64; ++ks) {
            const int cur = ks & 1, nxt = cur ^ 1;
            if (ks < 63) {
                const int o = (ks + 1) << 6;
#pragma unroll
                for (int rt = 0; rt < 2; ++rt) af[nxt][rt] = aBase[rt * 4096 + o];
#pragma unroll
                for (int ct = 0; ct < 4; ++ct) bf[nxt][ct] = bBase[ct * 4096 + o];
            }
#pragma unroll
            for (int rt = 0; rt < 2; ++rt)
#pragma unroll
                for (int ct = 0; ct < 4; ++ct)
                    acc[rt][ct] = __builtin_amdgcn_mfma_f32_32x32x16_f16(
                        af[cur][rt], bf[cur][ct], acc[rt][ct], 0, 0, 0);
        }

        float wsv[4], vav[4];
#pragma unroll
        for (int ct = 0; ct < 4; ++ct) {
            int n = (ntb + ct) << 5 | l31;
            wsv[ct] = wsWaS[b * 1024 + n];
            vav[ct] = Va[n];
        }
#pragma unroll
        for (int rt = 0; rt < 2; ++rt) {
#pragma unroll
            for (int i = 0; i < 16; ++i) {
                float s = 0.0f;
#pragma unroll
                for (int ct = 0; ct < 4; ++ct)
                    s += tanh_fast(acc[rt][ct][i] + wsv[ct]) * vav[ct];
                s += __shfl_xor(s, 1);
                s += __shfl_xor(s, 2);
                s += __shfl_xor(s, 4);
                s += __shfl_xor(s, 8);
                s += __shfl_xor(s, 16);
                if (l31 == 0) {
                    // 32x32 C/D: row=(reg&3)+8*(reg>>2)+4*(lane>>5)  [m74/m101]
                    int row = rt * 32 + (i & 3) + ((i >> 2) << 3) + (lhi << 2);
                    atomicAdd(&scoreSh[row], s);
                }
            }
        }
    }
    __syncthreads();
    if (tid < 64) scores[r0 + tid] = fmaxf(scoreSh[tid], 0.0f);
}

// ---- softmax over T=512 per batch ----
__global__ __launch_bounds__(256) void k_softmax(const float* __restrict__ scores,
                                                 float* __restrict__ sm) {
    int b = blockIdx.x, tid = threadIdx.x;
    __shared__ float red[256];
    const float* sb = scores + b * 512;
    float s0 = sb[tid], s1 = sb[tid + 256];
    red[tid] = fmaxf(s0, s1);
    __syncthreads();
    for (int st = 128; st > 0; st >>= 1) {
        if (tid < st) red[tid] = fmaxf(red[tid], red[tid + st]);
        __syncthreads();
    }
    float m = red[0];
    __syncthreads();
    float e0 = __expf(s0 - m), e1 = __expf(s1 - m);
    red[tid] = e0 + e1;
    __syncthreads();
    for (int st = 128; st > 0; st >>= 1) {
        if (tid < st) red[tid] += red[tid + st];
        __syncthreads();
    }
    float inv = 1.0f / red[0];
    sm[b * 512 + tid] = e0 * inv;
    sm[b * 512 + 256 + tid] = e1 * inv;
}

// ---- ctx from packed fp16 A16 ----
__global__ __launch_bounds__(256) void k_ctx(const _Float16* __restrict__ A16,
                                             const float* __restrict__ sm,
                                             float* __restrict__ out) {
    const int bx = blockIdx.x, b = blockIdx.y;
    const int tid = threadIdx.x, wv = tid >> 6, lane = tid & 63;
    const int l31 = lane & 31, lhi = lane >> 5;
    const h8* A8 = (const h8*)A16;
    const int ksl = bx * 4 + wv;
    float facc[8];
#pragma unroll
    for (int j = 0; j < 8; ++j) facc[j] = 0.0f;
    const float* smb = sm + b * 512;
#pragma unroll 4
    for (int rbl = 0; rbl < 16; ++rbl) {
        h8 x = A8[(((size_t)(b * 16 + rbl) << 6) + ksl) * 64 + lane];
        float wgt = smb[rbl * 32 + l31];
#pragma unroll
        for (int j = 0; j < 8; ++j) facc[j] += wgt * (float)x[j];
    }
#pragma unroll
    for (int m = 1; m < 32; m <<= 1)
#pragma unroll
        for (int j = 0; j < 8; ++j) facc[j] += __shfl_xor(facc[j], m);
    if (l31 == 0) {
        int oct = bx * 8 + wv * 2 + lhi;
        float* o = out + b * 1024 + oct * 8;
#pragma unroll
        for (int j = 0; j < 8; ++j) o[j] = facc[j];
    }
}

extern "C" void kernel_launch(void* const* d_in, const int* in_sizes, int n_in,
                              void* d_out, int out_size, void* d_ws, size_t ws_size,
                              hipStream_t stream) {
    const float* inputs = (const float*)d_in[0];
    const float* prev   = (const float*)d_in[1];
    const float* Wa     = (const float*)d_in[2];
    const float* Ua     = (const float*)d_in[3];
    const float* Va     = (const float*)d_in[4];
    const float* Ba     = (const float*)d_in[5];
    float* out = (float*)d_out;

    char* ws = (char*)d_ws;
    _Float16* A16 = (_Float16*)(ws);                         // 64 MB packed A
    _Float16* B16 = (_Float16*)(ws + (64u << 20));           // 2 MB packed Ua
    float* wsWaS  = (float*)(ws + (66u << 20));              // 256 KB
    float* scores = (float*)(ws + (66u << 20) + (256u << 10));   // 128 KB
    float* sm     = (float*)(ws + (66u << 20) + (384u << 10));   // 128 KB

    hipLaunchKernelGGL(k_pack_ua,    dim3(512),    dim3(256), 0, stream, Ua, B16);
    hipLaunchKernelGGL(k_pack_a,     dim3(1024),   dim3(256), 0, stream, inputs, A16);
    hipLaunchKernelGGL(k_was,        dim3(64),     dim3(256), 0, stream, prev, Wa, Ba, wsWaS);
    hipLaunchKernelGGL(k_fused_gemm, dim3(512),    dim3(256), 0, stream, A16, B16, wsWaS, Va, scores);
    hipLaunchKernelGGL(k_softmax,    dim3(64),     dim3(256), 0, stream, scores, sm);
    hipLaunchKernelGGL(k_ctx,        dim3(16, 64), dim3(256), 0, stream, A16, sm, out);
}